// Round 8
// baseline (147.064 us; speedup 1.0000x reference)
//
#include <hip/hip_runtime.h>
#include <cstdint>
#include <cstddef>

#define S_LEN 2047
#define BATCH 8
#define R_TOT 1162
#define NCHUNK 8
#define NEGV (-1e9f)

// ws layout: local = 8*2047*6*4 = 393,024 B at offset 0. (carry folded inline
// in mask_kernel — verified round 7.)

__device__ __constant__ int d_numerators[12] = {1, 2, 3, 4, 5, 6, 7, 8, 9, 10, 12, 16};

// nontemporal float2 store: single 8-byte store with nt flag (out is
// write-once/never-read — keep it out of L2/LLC so scores stay resident).
__device__ __forceinline__ void nt_store_f2(float2* p, float2 v) {
    union { float2 f; double d; } u;
    u.f = v;
    __builtin_nontemporal_store(u.d, reinterpret_cast<double*>(p));
}

// ---------------------------------------------------------------------------
// Kernel 1: within-chunk inclusive scan (64 blocks = 8 batches x 8 chunks).
// VERBATIM verified (rounds 0/3/7).
// ---------------------------------------------------------------------------
__global__ __launch_bounds__(256) void scan_local(const int* __restrict__ song,
                                                  unsigned* __restrict__ local) {
    const int b = blockIdx.x >> 3;
    const int c = blockIdx.x & 7;
    const int tid = threadIdx.x;
    const int j = c * 256 + tid;
    __shared__ unsigned lds_f[3][256];
    __shared__ unsigned lds_inst[5][256];
    const unsigned HAS = 1u << 16;
    const long base = (long)b * S_LEN;

    unsigned e_f[3] = {0, 0, 0};
    unsigned e_inst[5] = {0, 0, 0, 0, 0};
    if (j < S_LEN) {
        const int* rj = song + (base + j) * 11;
        const int type = rj[0];
        if (type == 4)      e_f[0] = HAS | (unsigned)rj[8];
        else if (type == 5) e_f[1] = HAS | (unsigned)rj[9];
        else if (type == 6) e_f[2] = HAS | (unsigned)rj[10];
        else if (type == 1) { const int v = rj[6]; e_inst[v >> 5] = 1u << (v & 31); }
    }
#pragma unroll
    for (int w = 0; w < 3; w++) lds_f[w][tid] = e_f[w];
#pragma unroll
    for (int w = 0; w < 5; w++) lds_inst[w][tid] = e_inst[w];
    __syncthreads();

    for (int off = 1; off < 256; off <<= 1) {
        unsigned p_f[3] = {0, 0, 0};
        unsigned p_inst[5] = {0, 0, 0, 0, 0};
        if (tid >= off) {
#pragma unroll
            for (int w = 0; w < 3; w++) p_f[w] = lds_f[w][tid - off];
#pragma unroll
            for (int w = 0; w < 5; w++) p_inst[w] = lds_inst[w][tid - off];
        }
        __syncthreads();
        if (tid >= off) {
#pragma unroll
            for (int w = 0; w < 3; w++) {
                if (!(e_f[w] & HAS)) e_f[w] = p_f[w];
                lds_f[w][tid] = e_f[w];
            }
#pragma unroll
            for (int w = 0; w < 5; w++) {
                e_inst[w] |= p_inst[w];
                lds_inst[w][tid] = e_inst[w];
            }
        }
        __syncthreads();
    }

    if (j < S_LEN) {
        const unsigned w0 =
            (e_f[0] & 0xFFu) | ((e_f[1] & 0xFFu) << 8) | ((e_f[2] & 0xFFu) << 16) |
            (((e_f[0] >> 16) & 1u) << 24) | (((e_f[1] >> 16) & 1u) << 25) |
            (((e_f[2] >> 16) & 1u) << 26);
        unsigned* sp = local + (size_t)(base + j) * 6;
        sp[0] = w0;
#pragma unroll
        for (int w = 0; w < 5; w++) sp[1 + w] = e_inst[w];
    }
}

// ---------------------------------------------------------------------------
// Kernel 2: round-7 VERIFIED mask kernel (inline carry fold), one surgical
// change: all out-stores are nontemporal (nt_store_f2). Everything else is
// byte-identical to round 7.
// ---------------------------------------------------------------------------
__global__ __launch_bounds__(256) void mask_kernel(const int* __restrict__ song,
                                                   const int* __restrict__ ctype,
                                                   const float* __restrict__ scores,
                                                   const unsigned* __restrict__ local,
                                                   float* __restrict__ out) {
    const int row = blockIdx.x;
    const int tid = threadIdx.x;
    const int b = row / S_LEN;
    const int i = row - b * S_LEN;

    __shared__ float s_val[128];
    __shared__ int   s_idx[128];
    __shared__ float sb_val[8];
    __shared__ int   sb_idx[8];
    __shared__ int   s_info[10];
    __shared__ int   f_info[17];

    const size_t rbase = (size_t)row * R_TOT;
    const float2* s2 = (const float2*)(scores + rbase);
    float2* o2 = (float2*)(out + rbase);

    const int t0 = ctype[row];  // wave-uniform scalar load; block-uniform branch

    const float2 r0 = s2[tid];
    const float2 r1 = s2[tid + 256];
    float2 r2 = make_float2(0.f, 0.f);
    if (tid < 69) r2 = s2[tid + 512];

    // ---- fast path: all masks all-true -> straight copy, zero barriers ----
    if (t0 == 0 || t0 == 2 || t0 == 7) {
        nt_store_f2(o2 + tid, r0);
        nt_store_f2(o2 + tid + 256, r1);
        if (tid < 69) nt_store_f2(o2 + tid + 512, r2);
        return;
    }

    if (tid < 128) {
        // measure candidates: cols 2*tid, 2*tid+1 (first index wins ties)
        const bool sec = (r0.y > r0.x);
        s_val[tid] = sec ? r0.y : r0.x;
        s_idx[tid] = 2 * tid + (sec ? 1 : 0);
    } else if (tid < 136) {
        // beat candidates: beat-relative cols 2*(tid-128), +1
        const bool sec = (r0.y > r0.x);
        sb_val[tid - 128] = sec ? r0.y : r0.x;
        sb_idx[tid - 128] = (2 * tid - 256) + (sec ? 1 : 0);
    } else if (tid < 142) {
        const int w = tid - 136;
        const int e = min(i + 1, S_LEN - 1);
        const int ch = e >> 8;  // fold aggregates of chunks [0, ch)
        const unsigned lw = local[((size_t)b * S_LEN + e) * 6 + w];
        unsigned v;
        if (w == 0) {
            // inline scan_carry fold, word 0 (verbatim verified round-7 math)
            const int* r0p = song + (size_t)b * S_LEN * 11;
            unsigned cks = (unsigned)r0p[8], cts = (unsigned)r0p[9], ctp = (unsigned)r0p[10];
            unsigned chas = 0;
            for (int cc = 0; cc < ch; cc++) {
                const unsigned a0 = local[((size_t)b * S_LEN + ((cc + 1) * 256 - 1)) * 6];
                if ((a0 >> 24) & 1u) cks = a0 & 0xFFu;
                if ((a0 >> 25) & 1u) cts = (a0 >> 8) & 0xFFu;
                if ((a0 >> 26) & 1u) ctp = (a0 >> 16) & 0xFFu;
                chas |= (a0 >> 24) & 7u;
            }
            const unsigned cw = (cks & 0xFFu) | ((cts & 0xFFu) << 8) |
                                ((ctp & 0xFFu) << 16) | (chas << 24);
            const unsigned ks = ((lw >> 24) & 1u) ? (lw & 0xFFu) : (cw & 0xFFu);
            const unsigned ts = ((lw >> 25) & 1u) ? ((lw >> 8) & 0xFFu) : ((cw >> 8) & 0xFFu);
            const unsigned tp = ((lw >> 26) & 1u) ? ((lw >> 16) & 0xFFu) : ((cw >> 16) & 0xFFu);
            const unsigned hks = ((lw >> 24) | (cw >> 24)) & 1u;
            const unsigned hts = ((lw >> 25) | (cw >> 25)) & 1u;
            v = ks | (ts << 8) | (tp << 16) | (hks << 24) | (hts << 25);
        } else {
            // inline scan_carry fold, words 1..5: OR of chunk-end aggregates
            unsigned cw = 0;
            for (int cc = 0; cc < ch; cc++) {
                cw |= local[((size_t)b * S_LEN + ((cc + 1) * 256 - 1)) * 6 + w];
            }
            v = lw | cw;
        }
        s_info[w] = (int)v;
    } else if (tid < 146) {
        const int* srow = song + (size_t)row * 11;
        if (tid == 142) s_info[6] = srow[1];
        if (tid == 143) s_info[7] = srow[2];
        if (tid == 144) s_info[8] = srow[3];
        if (tid == 145) s_info[9] = ctype[row];
    }
    __syncthreads();

    // 7-barrier reduction tree: only the t==3 path consumes pred_m/pred_b.
    if (t0 == 3) {
        for (int s = 64; s > 0; s >>= 1) {
            if (tid < s) {
                if (s_val[tid + s] > s_val[tid]) {  // strict > keeps lower index on tie
                    s_val[tid] = s_val[tid + s];
                    s_idx[tid] = s_idx[tid + s];
                }
            }
            __syncthreads();
        }
    }

    if (tid == 0) {
        int pred_m = -1, pred_b = -1;  // t!=3: never matches song fields (>=0)
        if (t0 == 3) {
            pred_m = s_idx[0];
            float bv = sb_val[0];
            pred_b = sb_idx[0];
#pragma unroll
            for (int q = 1; q < 8; q++) {
                if (sb_val[q] > bv) { bv = sb_val[q]; pred_b = sb_idx[q]; }
            }
        }
        const unsigned pack = (unsigned)s_info[0];
        const int song1 = s_info[6], song2 = s_info[7], song3 = s_info[8];
        const int t = s_info[9];
        const bool c1 = (pred_m == song1);
        const int min_beat = c1 ? song2 : 0;
        const bool c2 = c1 && (pred_b == min_beat);
        const int min_pos = c2 ? song3 : 0;
        const int last_ks = pack & 0xFF;
        const int last_ts = (pack >> 8) & 0xFF;
        const int last_tp = (pack >> 16) & 0xFF;
        f_info[0] = t;
        f_info[1] = song1;       // min_measure
        f_info[2] = min_beat;
        f_info[3] = min_pos;
        f_info[4] = (song2 == 0 && song3 == 0) ? song1 : song1 + 1;  // min_m46
        f_info[5] = d_numerators[last_ts % 12];                      // max_beat
        f_info[6] = last_ks;
        f_info[7] = last_ts;
        f_info[8] = last_tp;
        f_info[9]  = (int)((pack >> 24) & 1u);  // has_ks
        f_info[10] = (int)((pack >> 25) & 1u);  // has_ts
        const unsigned u = (unsigned)s_info[1] | (unsigned)s_info[2] | (unsigned)s_info[3] |
                           (unsigned)s_info[4] | (unsigned)s_info[5];
        f_info[11] = (u != 0u);                 // has_inst
        f_info[12] = s_info[1]; f_info[13] = s_info[2]; f_info[14] = s_info[3];
        f_info[15] = s_info[4]; f_info[16] = s_info[5];
    }
    __syncthreads();

    const int t = f_info[0];
    const int min_measure = f_info[1], min_beat = f_info[2], min_pos = f_info[3];
    const int min_m46 = f_info[4], max_beat = f_info[5];
    const int last_ks = f_info[6], last_ts = f_info[7], last_tp = f_info[8];
    const bool has_ks = f_info[9] != 0, has_ts = f_info[10] != 0, has_inst = f_info[11] != 0;
    unsigned inst[5];
#pragma unroll
    for (int w = 0; w < 5; w++) inst[w] = (unsigned)f_info[12 + w];
    const bool is3 = (t == 3);
    const bool is46 = (t >= 4) && (t <= 6);

    // Range offsets: measure 0..256, beat 256..272, position 272..400,
    // duration 400..528, pitch 528..784, instrument 784..913,
    // velocity 913..1041, key_sign 1041..1065, time_sign 1065..1113,
    // tempo 1113..1162
    auto maskf = [&](int col) -> bool {
        if (col < 256) {
            if (is3) return col >= min_measure;
            if (is46) return col >= min_m46;
            return true;
        } else if (col < 272) {
            if (!is3) return true;
            const int v = col - 256;
            return (v >= min_beat) && (v < max_beat);
        } else if (col < 400) {
            return is3 ? ((col - 272) >= min_pos) : true;
        } else if (col < 784) {
            return true;  // duration + pitch
        } else if (col < 913) {
            const int v = col - 784;
            const bool pres = ((inst[v >> 5] >> (v & 31)) & 1u) != 0u;
            if (is3) return pres;
            if (t == 1) return has_inst ? !pres : true;
            return true;
        } else if (col < 1041) {
            return true;  // velocity
        } else if (col < 1065) {
            const int v = col - 1041;
            if (is3) return v == last_ks;
            if (t == 4) return has_ks ? (v != last_ks) : true;
            return true;
        } else if (col < 1113) {
            const int v = col - 1065;
            if (is3) return v == last_ts;
            if (t == 5) return has_ts ? (v != last_ts) : true;
            return true;
        } else {
            const int v = col - 1113;
            if (is3) return v == last_tp;
            if (t == 6) return v != last_tp;  // no has-check for tempo
            return true;
        }
    };

    float2 w;
    int c = 2 * tid;
    w.x = maskf(c)     ? r0.x : NEGV;
    w.y = maskf(c + 1) ? r0.y : NEGV;
    nt_store_f2(o2 + tid, w);

    c = 512 + 2 * tid;
    w.x = maskf(c)     ? r1.x : NEGV;
    w.y = maskf(c + 1) ? r1.y : NEGV;
    nt_store_f2(o2 + tid + 256, w);

    if (tid < 69) {
        c = 1024 + 2 * tid;
        w.x = maskf(c)     ? r2.x : NEGV;
        w.y = maskf(c + 1) ? r2.y : NEGV;
        nt_store_f2(o2 + tid + 512, w);
    }
}

extern "C" void kernel_launch(void* const* d_in, const int* in_sizes, int n_in,
                              void* d_out, int out_size, void* d_ws, size_t ws_size,
                              hipStream_t stream) {
    const int* song = (const int*)d_in[0];
    const int* ctype = (const int*)d_in[1];
    const float* scores = (const float*)d_in[2];
    float* out = (float*)d_out;
    unsigned* local = (unsigned*)d_ws;  // 393,024 B

    scan_local<<<BATCH * NCHUNK, 256, 0, stream>>>(song, local);
    mask_kernel<<<BATCH * S_LEN, 256, 0, stream>>>(song, ctype, scores, local, out);
}

// Round 9
// 145.540 us; speedup vs baseline: 1.0105x; 1.0105x over previous
//
#include <hip/hip_runtime.h>
#include <cstdint>
#include <cstddef>

#define S_LEN 2047
#define BATCH 8
#define R_TOT 1162
#define NCHUNK 8
#define NEGV (-1e9f)

// ws layout: local = 8*2047*6*4 = 393,024 B at offset 0. (carry folded inline
// in mask_kernel — verified round 7.)

__device__ __constant__ int d_numerators[12] = {1, 2, 3, 4, 5, 6, 7, 8, 9, 10, 12, 16};

// ---------------------------------------------------------------------------
// Kernel 1: within-chunk inclusive scan (64 blocks = 8 batches x 8 chunks).
// VERBATIM verified (rounds 0/3/7).
// ---------------------------------------------------------------------------
__global__ __launch_bounds__(256) void scan_local(const int* __restrict__ song,
                                                  unsigned* __restrict__ local) {
    const int b = blockIdx.x >> 3;
    const int c = blockIdx.x & 7;
    const int tid = threadIdx.x;
    const int j = c * 256 + tid;
    __shared__ unsigned lds_f[3][256];
    __shared__ unsigned lds_inst[5][256];
    const unsigned HAS = 1u << 16;
    const long base = (long)b * S_LEN;

    unsigned e_f[3] = {0, 0, 0};
    unsigned e_inst[5] = {0, 0, 0, 0, 0};
    if (j < S_LEN) {
        const int* rj = song + (base + j) * 11;
        const int type = rj[0];
        if (type == 4)      e_f[0] = HAS | (unsigned)rj[8];
        else if (type == 5) e_f[1] = HAS | (unsigned)rj[9];
        else if (type == 6) e_f[2] = HAS | (unsigned)rj[10];
        else if (type == 1) { const int v = rj[6]; e_inst[v >> 5] = 1u << (v & 31); }
    }
#pragma unroll
    for (int w = 0; w < 3; w++) lds_f[w][tid] = e_f[w];
#pragma unroll
    for (int w = 0; w < 5; w++) lds_inst[w][tid] = e_inst[w];
    __syncthreads();

    for (int off = 1; off < 256; off <<= 1) {
        unsigned p_f[3] = {0, 0, 0};
        unsigned p_inst[5] = {0, 0, 0, 0, 0};
        if (tid >= off) {
#pragma unroll
            for (int w = 0; w < 3; w++) p_f[w] = lds_f[w][tid - off];
#pragma unroll
            for (int w = 0; w < 5; w++) p_inst[w] = lds_inst[w][tid - off];
        }
        __syncthreads();
        if (tid >= off) {
#pragma unroll
            for (int w = 0; w < 3; w++) {
                if (!(e_f[w] & HAS)) e_f[w] = p_f[w];
                lds_f[w][tid] = e_f[w];
            }
#pragma unroll
            for (int w = 0; w < 5; w++) {
                e_inst[w] |= p_inst[w];
                lds_inst[w][tid] = e_inst[w];
            }
        }
        __syncthreads();
    }

    if (j < S_LEN) {
        const unsigned w0 =
            (e_f[0] & 0xFFu) | ((e_f[1] & 0xFFu) << 8) | ((e_f[2] & 0xFFu) << 16) |
            (((e_f[0] >> 16) & 1u) << 24) | (((e_f[1] >> 16) & 1u) << 25) |
            (((e_f[2] >> 16) & 1u) << 26);
        unsigned* sp = local + (size_t)(base + j) * 6;
        sp[0] = w0;
#pragma unroll
        for (int w = 0; w < 5; w++) sp[1 + w] = e_inst[w];
    }
}

// ---------------------------------------------------------------------------
// Kernel 2: round-7 VERIFIED mask kernel (inline carry fold). Byte-identical
// to round 7 (nt stores from round 8 reverted — measured neutral-to-harmful).
//   t in {0,2,7}: pure copy, return before any barrier.
//   t != 3      : skip the 7-barrier argmax tree.
//   t == 3      : full verified path.
// ---------------------------------------------------------------------------
__global__ __launch_bounds__(256) void mask_kernel(const int* __restrict__ song,
                                                   const int* __restrict__ ctype,
                                                   const float* __restrict__ scores,
                                                   const unsigned* __restrict__ local,
                                                   float* __restrict__ out) {
    const int row = blockIdx.x;
    const int tid = threadIdx.x;
    const int b = row / S_LEN;
    const int i = row - b * S_LEN;

    __shared__ float s_val[128];
    __shared__ int   s_idx[128];
    __shared__ float sb_val[8];
    __shared__ int   sb_idx[8];
    __shared__ int   s_info[10];
    __shared__ int   f_info[17];

    const size_t rbase = (size_t)row * R_TOT;
    const float2* s2 = (const float2*)(scores + rbase);
    float2* o2 = (float2*)(out + rbase);

    const int t0 = ctype[row];  // wave-uniform scalar load; block-uniform branch

    const float2 r0 = s2[tid];
    const float2 r1 = s2[tid + 256];
    float2 r2 = make_float2(0.f, 0.f);
    if (tid < 69) r2 = s2[tid + 512];

    // ---- fast path: all masks all-true -> straight copy, zero barriers ----
    if (t0 == 0 || t0 == 2 || t0 == 7) {
        o2[tid] = r0;
        o2[tid + 256] = r1;
        if (tid < 69) o2[tid + 512] = r2;
        return;
    }

    if (tid < 128) {
        // measure candidates: cols 2*tid, 2*tid+1 (first index wins ties)
        const bool sec = (r0.y > r0.x);
        s_val[tid] = sec ? r0.y : r0.x;
        s_idx[tid] = 2 * tid + (sec ? 1 : 0);
    } else if (tid < 136) {
        // beat candidates: beat-relative cols 2*(tid-128), +1
        const bool sec = (r0.y > r0.x);
        sb_val[tid - 128] = sec ? r0.y : r0.x;
        sb_idx[tid - 128] = (2 * tid - 256) + (sec ? 1 : 0);
    } else if (tid < 142) {
        const int w = tid - 136;
        const int e = min(i + 1, S_LEN - 1);
        const int ch = e >> 8;  // fold aggregates of chunks [0, ch)
        const unsigned lw = local[((size_t)b * S_LEN + e) * 6 + w];
        unsigned v;
        if (w == 0) {
            // inline scan_carry fold, word 0 (verbatim verified round-7 math)
            const int* r0p = song + (size_t)b * S_LEN * 11;
            unsigned cks = (unsigned)r0p[8], cts = (unsigned)r0p[9], ctp = (unsigned)r0p[10];
            unsigned chas = 0;
            for (int cc = 0; cc < ch; cc++) {
                const unsigned a0 = local[((size_t)b * S_LEN + ((cc + 1) * 256 - 1)) * 6];
                if ((a0 >> 24) & 1u) cks = a0 & 0xFFu;
                if ((a0 >> 25) & 1u) cts = (a0 >> 8) & 0xFFu;
                if ((a0 >> 26) & 1u) ctp = (a0 >> 16) & 0xFFu;
                chas |= (a0 >> 24) & 7u;
            }
            const unsigned cw = (cks & 0xFFu) | ((cts & 0xFFu) << 8) |
                                ((ctp & 0xFFu) << 16) | (chas << 24);
            const unsigned ks = ((lw >> 24) & 1u) ? (lw & 0xFFu) : (cw & 0xFFu);
            const unsigned ts = ((lw >> 25) & 1u) ? ((lw >> 8) & 0xFFu) : ((cw >> 8) & 0xFFu);
            const unsigned tp = ((lw >> 26) & 1u) ? ((lw >> 16) & 0xFFu) : ((cw >> 16) & 0xFFu);
            const unsigned hks = ((lw >> 24) | (cw >> 24)) & 1u;
            const unsigned hts = ((lw >> 25) | (cw >> 25)) & 1u;
            v = ks | (ts << 8) | (tp << 16) | (hks << 24) | (hts << 25);
        } else {
            // inline scan_carry fold, words 1..5: OR of chunk-end aggregates
            unsigned cw = 0;
            for (int cc = 0; cc < ch; cc++) {
                cw |= local[((size_t)b * S_LEN + ((cc + 1) * 256 - 1)) * 6 + w];
            }
            v = lw | cw;
        }
        s_info[w] = (int)v;
    } else if (tid < 146) {
        const int* srow = song + (size_t)row * 11;
        if (tid == 142) s_info[6] = srow[1];
        if (tid == 143) s_info[7] = srow[2];
        if (tid == 144) s_info[8] = srow[3];
        if (tid == 145) s_info[9] = ctype[row];
    }
    __syncthreads();

    // 7-barrier reduction tree: only the t==3 path consumes pred_m/pred_b.
    if (t0 == 3) {
        for (int s = 64; s > 0; s >>= 1) {
            if (tid < s) {
                if (s_val[tid + s] > s_val[tid]) {  // strict > keeps lower index on tie
                    s_val[tid] = s_val[tid + s];
                    s_idx[tid] = s_idx[tid + s];
                }
            }
            __syncthreads();
        }
    }

    if (tid == 0) {
        int pred_m = -1, pred_b = -1;  // t!=3: never matches song fields (>=0)
        if (t0 == 3) {
            pred_m = s_idx[0];
            float bv = sb_val[0];
            pred_b = sb_idx[0];
#pragma unroll
            for (int q = 1; q < 8; q++) {
                if (sb_val[q] > bv) { bv = sb_val[q]; pred_b = sb_idx[q]; }
            }
        }
        const unsigned pack = (unsigned)s_info[0];
        const int song1 = s_info[6], song2 = s_info[7], song3 = s_info[8];
        const int t = s_info[9];
        const bool c1 = (pred_m == song1);
        const int min_beat = c1 ? song2 : 0;
        const bool c2 = c1 && (pred_b == min_beat);
        const int min_pos = c2 ? song3 : 0;
        const int last_ks = pack & 0xFF;
        const int last_ts = (pack >> 8) & 0xFF;
        const int last_tp = (pack >> 16) & 0xFF;
        f_info[0] = t;
        f_info[1] = song1;       // min_measure
        f_info[2] = min_beat;
        f_info[3] = min_pos;
        f_info[4] = (song2 == 0 && song3 == 0) ? song1 : song1 + 1;  // min_m46
        f_info[5] = d_numerators[last_ts % 12];                      // max_beat
        f_info[6] = last_ks;
        f_info[7] = last_ts;
        f_info[8] = last_tp;
        f_info[9]  = (int)((pack >> 24) & 1u);  // has_ks
        f_info[10] = (int)((pack >> 25) & 1u);  // has_ts
        const unsigned u = (unsigned)s_info[1] | (unsigned)s_info[2] | (unsigned)s_info[3] |
                           (unsigned)s_info[4] | (unsigned)s_info[5];
        f_info[11] = (u != 0u);                 // has_inst
        f_info[12] = s_info[1]; f_info[13] = s_info[2]; f_info[14] = s_info[3];
        f_info[15] = s_info[4]; f_info[16] = s_info[5];
    }
    __syncthreads();

    const int t = f_info[0];
    const int min_measure = f_info[1], min_beat = f_info[2], min_pos = f_info[3];
    const int min_m46 = f_info[4], max_beat = f_info[5];
    const int last_ks = f_info[6], last_ts = f_info[7], last_tp = f_info[8];
    const bool has_ks = f_info[9] != 0, has_ts = f_info[10] != 0, has_inst = f_info[11] != 0;
    unsigned inst[5];
#pragma unroll
    for (int w = 0; w < 5; w++) inst[w] = (unsigned)f_info[12 + w];
    const bool is3 = (t == 3);
    const bool is46 = (t >= 4) && (t <= 6);

    // Range offsets: measure 0..256, beat 256..272, position 272..400,
    // duration 400..528, pitch 528..784, instrument 784..913,
    // velocity 913..1041, key_sign 1041..1065, time_sign 1065..1113,
    // tempo 1113..1162
    auto maskf = [&](int col) -> bool {
        if (col < 256) {
            if (is3) return col >= min_measure;
            if (is46) return col >= min_m46;
            return true;
        } else if (col < 272) {
            if (!is3) return true;
            const int v = col - 256;
            return (v >= min_beat) && (v < max_beat);
        } else if (col < 400) {
            return is3 ? ((col - 272) >= min_pos) : true;
        } else if (col < 784) {
            return true;  // duration + pitch
        } else if (col < 913) {
            const int v = col - 784;
            const bool pres = ((inst[v >> 5] >> (v & 31)) & 1u) != 0u;
            if (is3) return pres;
            if (t == 1) return has_inst ? !pres : true;
            return true;
        } else if (col < 1041) {
            return true;  // velocity
        } else if (col < 1065) {
            const int v = col - 1041;
            if (is3) return v == last_ks;
            if (t == 4) return has_ks ? (v != last_ks) : true;
            return true;
        } else if (col < 1113) {
            const int v = col - 1065;
            if (is3) return v == last_ts;
            if (t == 5) return has_ts ? (v != last_ts) : true;
            return true;
        } else {
            const int v = col - 1113;
            if (is3) return v == last_tp;
            if (t == 6) return v != last_tp;  // no has-check for tempo
            return true;
        }
    };

    float2 w;
    int c = 2 * tid;
    w.x = maskf(c)     ? r0.x : NEGV;
    w.y = maskf(c + 1) ? r0.y : NEGV;
    o2[tid] = w;

    c = 512 + 2 * tid;
    w.x = maskf(c)     ? r1.x : NEGV;
    w.y = maskf(c + 1) ? r1.y : NEGV;
    o2[tid + 256] = w;

    if (tid < 69) {
        c = 1024 + 2 * tid;
        w.x = maskf(c)     ? r2.x : NEGV;
        w.y = maskf(c + 1) ? r2.y : NEGV;
        o2[tid + 512] = w;
    }
}

extern "C" void kernel_launch(void* const* d_in, const int* in_sizes, int n_in,
                              void* d_out, int out_size, void* d_ws, size_t ws_size,
                              hipStream_t stream) {
    const int* song = (const int*)d_in[0];
    const int* ctype = (const int*)d_in[1];
    const float* scores = (const float*)d_in[2];
    float* out = (float*)d_out;
    unsigned* local = (unsigned*)d_ws;  // 393,024 B

    scan_local<<<BATCH * NCHUNK, 256, 0, stream>>>(song, local);
    mask_kernel<<<BATCH * S_LEN, 256, 0, stream>>>(song, ctype, scores, local, out);
}

// Round 10
// 144.336 us; speedup vs baseline: 1.0189x; 1.0083x over previous
//
#include <hip/hip_runtime.h>
#include <cstdint>
#include <cstddef>

#define S_LEN 2047
#define BATCH 8
#define R_TOT 1162
#define NCHUNK 8
#define NEGV (-1e9f)

// ws layout: local = 8*2047*6*4 = 393,024 B at offset 0. (carry folded inline
// in mask_kernel — verified rounds 7/9.)

__device__ __constant__ int d_numerators[12] = {1, 2, 3, 4, 5, 6, 7, 8, 9, 10, 12, 16};

// ---------------------------------------------------------------------------
// Kernel 1: within-chunk inclusive scan (64 blocks = 8 batches x 8 chunks).
// VERBATIM verified (rounds 0/3/7/9).
// ---------------------------------------------------------------------------
__global__ __launch_bounds__(256) void scan_local(const int* __restrict__ song,
                                                  unsigned* __restrict__ local) {
    const int b = blockIdx.x >> 3;
    const int c = blockIdx.x & 7;
    const int tid = threadIdx.x;
    const int j = c * 256 + tid;
    __shared__ unsigned lds_f[3][256];
    __shared__ unsigned lds_inst[5][256];
    const unsigned HAS = 1u << 16;
    const long base = (long)b * S_LEN;

    unsigned e_f[3] = {0, 0, 0};
    unsigned e_inst[5] = {0, 0, 0, 0, 0};
    if (j < S_LEN) {
        const int* rj = song + (base + j) * 11;
        const int type = rj[0];
        if (type == 4)      e_f[0] = HAS | (unsigned)rj[8];
        else if (type == 5) e_f[1] = HAS | (unsigned)rj[9];
        else if (type == 6) e_f[2] = HAS | (unsigned)rj[10];
        else if (type == 1) { const int v = rj[6]; e_inst[v >> 5] = 1u << (v & 31); }
    }
#pragma unroll
    for (int w = 0; w < 3; w++) lds_f[w][tid] = e_f[w];
#pragma unroll
    for (int w = 0; w < 5; w++) lds_inst[w][tid] = e_inst[w];
    __syncthreads();

    for (int off = 1; off < 256; off <<= 1) {
        unsigned p_f[3] = {0, 0, 0};
        unsigned p_inst[5] = {0, 0, 0, 0, 0};
        if (tid >= off) {
#pragma unroll
            for (int w = 0; w < 3; w++) p_f[w] = lds_f[w][tid - off];
#pragma unroll
            for (int w = 0; w < 5; w++) p_inst[w] = lds_inst[w][tid - off];
        }
        __syncthreads();
        if (tid >= off) {
#pragma unroll
            for (int w = 0; w < 3; w++) {
                if (!(e_f[w] & HAS)) e_f[w] = p_f[w];
                lds_f[w][tid] = e_f[w];
            }
#pragma unroll
            for (int w = 0; w < 5; w++) {
                e_inst[w] |= p_inst[w];
                lds_inst[w][tid] = e_inst[w];
            }
        }
        __syncthreads();
    }

    if (j < S_LEN) {
        const unsigned w0 =
            (e_f[0] & 0xFFu) | ((e_f[1] & 0xFFu) << 8) | ((e_f[2] & 0xFFu) << 16) |
            (((e_f[0] >> 16) & 1u) << 24) | (((e_f[1] >> 16) & 1u) << 25) |
            (((e_f[2] >> 16) & 1u) << 26);
        unsigned* sp = local + (size_t)(base + j) * 6;
        sp[0] = w0;
#pragma unroll
        for (int w = 0; w < 5; w++) sp[1 + w] = e_inst[w];
    }
}

// ---------------------------------------------------------------------------
// Kernel 2: round-7/9 VERIFIED mask kernel with one surgical change:
//   t in {0,2,7}: pure copy, return before any barrier (verbatim).
//   t == 3      : full verified LDS/tree path (verbatim).
//   t in {1,4,5,6} (NEW): state computed redundantly per-thread — the
//     local/carry/song loads are wave-uniform (HW broadcast, L1/L2-hot) and
//     the fold math is the verbatim verified expressions. Zero barriers,
//     zero LDS, no tid-0 serialization on this path.
// Branch on t0 is block-uniform, so all remaining barriers stay uniform.
// ---------------------------------------------------------------------------
__global__ __launch_bounds__(256) void mask_kernel(const int* __restrict__ song,
                                                   const int* __restrict__ ctype,
                                                   const float* __restrict__ scores,
                                                   const unsigned* __restrict__ local,
                                                   float* __restrict__ out) {
    const int row = blockIdx.x;
    const int tid = threadIdx.x;
    const int b = row / S_LEN;
    const int i = row - b * S_LEN;

    __shared__ float s_val[128];
    __shared__ int   s_idx[128];
    __shared__ float sb_val[8];
    __shared__ int   sb_idx[8];
    __shared__ int   s_info[10];
    __shared__ int   f_info[17];

    const size_t rbase = (size_t)row * R_TOT;
    const float2* s2 = (const float2*)(scores + rbase);
    float2* o2 = (float2*)(out + rbase);

    const int t0 = ctype[row];  // wave-uniform scalar load; block-uniform branch

    const float2 r0 = s2[tid];
    const float2 r1 = s2[tid + 256];
    float2 r2 = make_float2(0.f, 0.f);
    if (tid < 69) r2 = s2[tid + 512];

    // ---- fast path: all masks all-true -> straight copy, zero barriers ----
    if (t0 == 0 || t0 == 2 || t0 == 7) {
        o2[tid] = r0;
        o2[tid + 256] = r1;
        if (tid < 69) o2[tid + 512] = r2;
        return;
    }

    // mask-field state (filled by one of the two paths below)
    int t, min_measure, min_beat, min_pos, min_m46, max_beat;
    int last_ks, last_ts, last_tp;
    bool has_ks, has_ts, has_inst;
    unsigned inst[5];

    if (t0 == 3) {
        // ================= verbatim verified round-7 state path =============
        if (tid < 128) {
            // measure candidates: cols 2*tid, 2*tid+1 (first index wins ties)
            const bool sec = (r0.y > r0.x);
            s_val[tid] = sec ? r0.y : r0.x;
            s_idx[tid] = 2 * tid + (sec ? 1 : 0);
        } else if (tid < 136) {
            // beat candidates: beat-relative cols 2*(tid-128), +1
            const bool sec = (r0.y > r0.x);
            sb_val[tid - 128] = sec ? r0.y : r0.x;
            sb_idx[tid - 128] = (2 * tid - 256) + (sec ? 1 : 0);
        } else if (tid < 142) {
            const int w = tid - 136;
            const int e = min(i + 1, S_LEN - 1);
            const int ch = e >> 8;  // fold aggregates of chunks [0, ch)
            const unsigned lw = local[((size_t)b * S_LEN + e) * 6 + w];
            unsigned v;
            if (w == 0) {
                // inline scan_carry fold, word 0 (verbatim verified math)
                const int* r0p = song + (size_t)b * S_LEN * 11;
                unsigned cks = (unsigned)r0p[8], cts = (unsigned)r0p[9], ctp = (unsigned)r0p[10];
                unsigned chas = 0;
                for (int cc = 0; cc < ch; cc++) {
                    const unsigned a0 = local[((size_t)b * S_LEN + ((cc + 1) * 256 - 1)) * 6];
                    if ((a0 >> 24) & 1u) cks = a0 & 0xFFu;
                    if ((a0 >> 25) & 1u) cts = (a0 >> 8) & 0xFFu;
                    if ((a0 >> 26) & 1u) ctp = (a0 >> 16) & 0xFFu;
                    chas |= (a0 >> 24) & 7u;
                }
                const unsigned cw = (cks & 0xFFu) | ((cts & 0xFFu) << 8) |
                                    ((ctp & 0xFFu) << 16) | (chas << 24);
                const unsigned ks = ((lw >> 24) & 1u) ? (lw & 0xFFu) : (cw & 0xFFu);
                const unsigned ts = ((lw >> 25) & 1u) ? ((lw >> 8) & 0xFFu) : ((cw >> 8) & 0xFFu);
                const unsigned tp = ((lw >> 26) & 1u) ? ((lw >> 16) & 0xFFu) : ((cw >> 16) & 0xFFu);
                const unsigned hks = ((lw >> 24) | (cw >> 24)) & 1u;
                const unsigned hts = ((lw >> 25) | (cw >> 25)) & 1u;
                v = ks | (ts << 8) | (tp << 16) | (hks << 24) | (hts << 25);
            } else {
                // inline scan_carry fold, words 1..5: OR of chunk-end aggregates
                unsigned cw = 0;
                for (int cc = 0; cc < ch; cc++) {
                    cw |= local[((size_t)b * S_LEN + ((cc + 1) * 256 - 1)) * 6 + w];
                }
                v = lw | cw;
            }
            s_info[w] = (int)v;
        } else if (tid < 146) {
            const int* srow = song + (size_t)row * 11;
            if (tid == 142) s_info[6] = srow[1];
            if (tid == 143) s_info[7] = srow[2];
            if (tid == 144) s_info[8] = srow[3];
            if (tid == 145) s_info[9] = ctype[row];
        }
        __syncthreads();

        // 7-barrier reduction tree (t0==3 here always)
        for (int s = 64; s > 0; s >>= 1) {
            if (tid < s) {
                if (s_val[tid + s] > s_val[tid]) {  // strict > keeps lower index on tie
                    s_val[tid] = s_val[tid + s];
                    s_idx[tid] = s_idx[tid + s];
                }
            }
            __syncthreads();
        }

        if (tid == 0) {
            const int pred_m = s_idx[0];
            float bv = sb_val[0];
            int pred_b = sb_idx[0];
#pragma unroll
            for (int q = 1; q < 8; q++) {
                if (sb_val[q] > bv) { bv = sb_val[q]; pred_b = sb_idx[q]; }
            }
            const unsigned pack = (unsigned)s_info[0];
            const int song1 = s_info[6], song2 = s_info[7], song3 = s_info[8];
            const int tt = s_info[9];
            const bool c1 = (pred_m == song1);
            const int mb = c1 ? song2 : 0;
            const bool c2 = c1 && (pred_b == mb);
            const int mp = c2 ? song3 : 0;
            const int lks = pack & 0xFF;
            const int lts = (pack >> 8) & 0xFF;
            const int ltp = (pack >> 16) & 0xFF;
            f_info[0] = tt;
            f_info[1] = song1;       // min_measure
            f_info[2] = mb;
            f_info[3] = mp;
            f_info[4] = (song2 == 0 && song3 == 0) ? song1 : song1 + 1;  // min_m46
            f_info[5] = d_numerators[lts % 12];                          // max_beat
            f_info[6] = lks;
            f_info[7] = lts;
            f_info[8] = ltp;
            f_info[9]  = (int)((pack >> 24) & 1u);  // has_ks
            f_info[10] = (int)((pack >> 25) & 1u);  // has_ts
            const unsigned u = (unsigned)s_info[1] | (unsigned)s_info[2] | (unsigned)s_info[3] |
                               (unsigned)s_info[4] | (unsigned)s_info[5];
            f_info[11] = (u != 0u);                 // has_inst
            f_info[12] = s_info[1]; f_info[13] = s_info[2]; f_info[14] = s_info[3];
            f_info[15] = s_info[4]; f_info[16] = s_info[5];
        }
        __syncthreads();

        t = f_info[0];
        min_measure = f_info[1]; min_beat = f_info[2]; min_pos = f_info[3];
        min_m46 = f_info[4]; max_beat = f_info[5];
        last_ks = f_info[6]; last_ts = f_info[7]; last_tp = f_info[8];
        has_ks = f_info[9] != 0; has_ts = f_info[10] != 0; has_inst = f_info[11] != 0;
#pragma unroll
        for (int w = 0; w < 5; w++) inst[w] = (unsigned)f_info[12 + w];
    } else {
        // ===== t in {1,4,5,6}: redundant per-thread state, zero barriers ====
        // All loads are wave-uniform addresses (one fetch, broadcast).
        const int e = min(i + 1, S_LEN - 1);
        const int ch = e >> 8;
        const unsigned* lp = local + ((size_t)b * S_LEN + e) * 6;
        const unsigned lw0 = lp[0];
        unsigned li[5];
#pragma unroll
        for (int w = 0; w < 5; w++) li[w] = lp[1 + w];

        // inline scan_carry fold (verbatim verified math)
        const int* r0p = song + (size_t)b * S_LEN * 11;
        unsigned cks = (unsigned)r0p[8], cts = (unsigned)r0p[9], ctp = (unsigned)r0p[10];
        unsigned chas = 0;
        unsigned cin[5] = {0, 0, 0, 0, 0};
        for (int cc = 0; cc < ch; cc++) {
            const unsigned* ap = local + ((size_t)b * S_LEN + ((cc + 1) * 256 - 1)) * 6;
            const unsigned a0 = ap[0];
            if ((a0 >> 24) & 1u) cks = a0 & 0xFFu;
            if ((a0 >> 25) & 1u) cts = (a0 >> 8) & 0xFFu;
            if ((a0 >> 26) & 1u) ctp = (a0 >> 16) & 0xFFu;
            chas |= (a0 >> 24) & 7u;
#pragma unroll
            for (int w = 0; w < 5; w++) cin[w] |= ap[1 + w];
        }
        // combine local + carry (verbatim select/OR semantics)
        last_ks = ((lw0 >> 24) & 1u) ? (int)(lw0 & 0xFFu) : (int)cks;
        last_ts = ((lw0 >> 25) & 1u) ? (int)((lw0 >> 8) & 0xFFu) : (int)cts;
        last_tp = ((lw0 >> 26) & 1u) ? (int)((lw0 >> 16) & 0xFFu) : (int)ctp;
        has_ks = ((((lw0 >> 24) & 1u) | (chas & 1u)) != 0u);
        has_ts = ((((lw0 >> 25) & 1u) | ((chas >> 1) & 1u)) != 0u);
        unsigned u = 0;
#pragma unroll
        for (int w = 0; w < 5; w++) { inst[w] = li[w] | cin[w]; u |= inst[w]; }
        has_inst = (u != 0u);

        const int* srow = song + (size_t)row * 11;
        const int song1 = srow[1], song2 = srow[2], song3 = srow[3];
        t = t0;
        // t != 3: pred_m = -1 -> c1 false -> min_beat = min_pos = 0 (verbatim)
        min_measure = song1;
        min_beat = 0;
        min_pos = 0;
        min_m46 = (song2 == 0 && song3 == 0) ? song1 : song1 + 1;
        max_beat = d_numerators[last_ts % 12];
    }

    const bool is3 = (t == 3);
    const bool is46 = (t >= 4) && (t <= 6);

    // Range offsets: measure 0..256, beat 256..272, position 272..400,
    // duration 400..528, pitch 528..784, instrument 784..913,
    // velocity 913..1041, key_sign 1041..1065, time_sign 1065..1113,
    // tempo 1113..1162
    auto maskf = [&](int col) -> bool {
        if (col < 256) {
            if (is3) return col >= min_measure;
            if (is46) return col >= min_m46;
            return true;
        } else if (col < 272) {
            if (!is3) return true;
            const int v = col - 256;
            return (v >= min_beat) && (v < max_beat);
        } else if (col < 400) {
            return is3 ? ((col - 272) >= min_pos) : true;
        } else if (col < 784) {
            return true;  // duration + pitch
        } else if (col < 913) {
            const int v = col - 784;
            const bool pres = ((inst[v >> 5] >> (v & 31)) & 1u) != 0u;
            if (is3) return pres;
            if (t == 1) return has_inst ? !pres : true;
            return true;
        } else if (col < 1041) {
            return true;  // velocity
        } else if (col < 1065) {
            const int v = col - 1041;
            if (is3) return v == last_ks;
            if (t == 4) return has_ks ? (v != last_ks) : true;
            return true;
        } else if (col < 1113) {
            const int v = col - 1065;
            if (is3) return v == last_ts;
            if (t == 5) return has_ts ? (v != last_ts) : true;
            return true;
        } else {
            const int v = col - 1113;
            if (is3) return v == last_tp;
            if (t == 6) return v != last_tp;  // no has-check for tempo
            return true;
        }
    };

    float2 w;
    int c = 2 * tid;
    w.x = maskf(c)     ? r0.x : NEGV;
    w.y = maskf(c + 1) ? r0.y : NEGV;
    o2[tid] = w;

    c = 512 + 2 * tid;
    w.x = maskf(c)     ? r1.x : NEGV;
    w.y = maskf(c + 1) ? r1.y : NEGV;
    o2[tid + 256] = w;

    if (tid < 69) {
        c = 1024 + 2 * tid;
        w.x = maskf(c)     ? r2.x : NEGV;
        w.y = maskf(c + 1) ? r2.y : NEGV;
        o2[tid + 512] = w;
    }
}

extern "C" void kernel_launch(void* const* d_in, const int* in_sizes, int n_in,
                              void* d_out, int out_size, void* d_ws, size_t ws_size,
                              hipStream_t stream) {
    const int* song = (const int*)d_in[0];
    const int* ctype = (const int*)d_in[1];
    const float* scores = (const float*)d_in[2];
    float* out = (float*)d_out;
    unsigned* local = (unsigned*)d_ws;  // 393,024 B

    scan_local<<<BATCH * NCHUNK, 256, 0, stream>>>(song, local);
    mask_kernel<<<BATCH * S_LEN, 256, 0, stream>>>(song, ctype, scores, local, out);
}